// Round 1
// baseline (234.535 us; speedup 1.0000x reference)
//
#include <hip/hip_runtime.h>

// Navier-Stokes physics-informed loss.
// x,y: (64,3,512,512) f32. std: scalar f32. out: scalar f32.
// Interior: b in [1,62], i in [1,510], j in [1,510]. N = 62*510*510.
// Residuals (fields pre-scaled by std; s folded into constants below):
//   r0 = |dudx + dvdy|
//   r1 = |dudt + u*dudx + v*dudy + dpdx - MU*(lap u)|
//   r2 = |dvdt + u*dvdx + v*dvdy + dpdy - MU*(lap v)|
// dudt = (u[b+1]-u[b-1]) * 32   (reference divides by DT, not 2*DT)
// d/dx,d/dy: central * 127.5 ; MU/DX^2 = 1e-5 * 65025 = 0.65025

constexpr int Wd   = 512;
constexpr int CSTR = 512 * 512;       // channel stride
constexpr int BSTR = 3 * 512 * 512;   // batch stride

__global__ __launch_bounds__(256)
void ns_loss_kernel(const float* __restrict__ X, const float* __restrict__ Y,
                    const float* __restrict__ stdp, double* __restrict__ acc)
{
    const float s    = *stdp;
    const float idt  = 32.0f;          // applied to already-scaled centers
    const float sdx  = s * 127.5f;     // std / (2*DX), applied to raw loads
    const float slap = s * 0.65025f;   // std * MU / DX^2, applied to raw loads
    const float lap4 = 4.0f * 0.65025f;// applied to scaled center

    const int tj    = blockIdx.x * 256 + threadIdx.x;  // 0..511
    const bool valid = (tj < 510);
    const int j  = 1 + (valid ? tj : 509);
    const int i  = 1 + blockIdx.y;            // 1..510
    const int b0 = 1 + 31 * blockIdx.z;       // 1 or 32; 31 b-steps each

    int c = b0 * BSTR + i * Wd + j;           // (b0, c=0, i, j)

    // register-carried scaled centers: u,v at b-1 and b, both tensors
    float xum = X[c - BSTR] * s,        xuc = X[c] * s;
    float xvm = X[c - BSTR + CSTR] * s, xvc = X[c + CSTR] * s;
    float yum = Y[c - BSTR] * s,        yuc = Y[c] * s;
    float yvm = Y[c - BSTR + CSTR] * s, yvc = Y[c + CSTR] * s;

    double s0 = 0.0, s1 = 0.0, s2 = 0.0;

    for (int it = 0; it < 31; ++it) {
        // ---------------- X ----------------
        float up  = X[c + BSTR] * s;
        float vp  = X[c + BSTR + CSTR] * s;
        float uxp = X[c + Wd],          uxm = X[c - Wd];
        float uyp = X[c + 1],           uym = X[c - 1];
        float vxp = X[c + CSTR + Wd],   vxm = X[c + CSTR - Wd];
        float vyp = X[c + CSTR + 1],    vym = X[c + CSTR - 1];
        float pxp = X[c + 2*CSTR + Wd], pxm = X[c + 2*CSTR - Wd];
        float pyp = X[c + 2*CSTR + 1],  pym = X[c + 2*CSTR - 1];

        float dudx = (uxp - uxm) * sdx;
        float dudy = (uyp - uym) * sdx;
        float dvdx = (vxp - vxm) * sdx;
        float dvdy = (vyp - vym) * sdx;
        float lapu = (uxp + uxm + uyp + uym) * slap - lap4 * xuc;
        float lapv = (vxp + vxm + vyp + vym) * slap - lap4 * xvc;
        float r0x = fabsf(dudx + dvdy);
        float r1x = fabsf((up - xum) * idt + xuc * dudx + xvc * dudy
                          + (pxp - pxm) * sdx - lapu);
        float r2x = fabsf((vp - xvm) * idt + xuc * dvdx + xvc * dvdy
                          + (pyp - pym) * sdx - lapv);
        xum = xuc; xuc = up; xvm = xvc; xvc = vp;

        // ---------------- Y ----------------
        up  = Y[c + BSTR] * s;
        vp  = Y[c + BSTR + CSTR] * s;
        uxp = Y[c + Wd];          uxm = Y[c - Wd];
        uyp = Y[c + 1];           uym = Y[c - 1];
        vxp = Y[c + CSTR + Wd];   vxm = Y[c + CSTR - Wd];
        vyp = Y[c + CSTR + 1];    vym = Y[c + CSTR - 1];
        pxp = Y[c + 2*CSTR + Wd]; pxm = Y[c + 2*CSTR - Wd];
        pyp = Y[c + 2*CSTR + 1];  pym = Y[c + 2*CSTR - 1];

        float dudxY = (uxp - uxm) * sdx;
        float dudyY = (uyp - uym) * sdx;
        float dvdxY = (vxp - vxm) * sdx;
        float dvdyY = (vyp - vym) * sdx;
        float lapuY = (uxp + uxm + uyp + uym) * slap - lap4 * yuc;
        float lapvY = (vxp + vxm + vyp + vym) * slap - lap4 * yvc;
        float r0y = fabsf(dudxY + dvdyY);
        float r1y = fabsf((up - yum) * idt + yuc * dudxY + yvc * dudyY
                          + (pxp - pxm) * sdx - lapuY);
        float r2y = fabsf((vp - yvm) * idt + yuc * dvdxY + yvc * dvdyY
                          + (pyp - pym) * sdx - lapvY);
        yum = yuc; yuc = up; yvm = yvc; yvc = vp;

        float e0 = r0y - r0x, e1 = r1y - r1x, e2 = r2y - r2x;
        if (valid) {
            s0 += (double)e0 * (double)e0;
            s1 += (double)e1 * (double)e1;
            s2 += (double)e2 * (double)e2;
        }
        c += BSTR;
    }

    // ---- block reduction: wave shuffle -> LDS -> one atomic per block ----
    for (int o = 32; o > 0; o >>= 1) {
        s0 += __shfl_down(s0, o);
        s1 += __shfl_down(s1, o);
        s2 += __shfl_down(s2, o);
    }
    __shared__ double sm[3][4];
    const int wid = threadIdx.x >> 6, lane = threadIdx.x & 63;
    if (lane == 0) { sm[0][wid] = s0; sm[1][wid] = s1; sm[2][wid] = s2; }
    __syncthreads();
    if (threadIdx.x == 0) {
        double t0 = sm[0][0] + sm[0][1] + sm[0][2] + sm[0][3];
        double t1 = sm[1][0] + sm[1][1] + sm[1][2] + sm[1][3];
        double t2 = sm[2][0] + sm[2][1] + sm[2][2] + sm[2][3];
        atomicAdd(&acc[0], t0);
        atomicAdd(&acc[1], t1);
        atomicAdd(&acc[2], t2);
    }
}

__global__ void ns_finalize_kernel(const double* __restrict__ acc,
                                   float* __restrict__ out)
{
    if (threadIdx.x == 0) {
        const double N = 62.0 * 510.0 * 510.0;
        out[0] = (float)(1.0e-3 * (acc[0] + acc[1] + acc[2]) / N);
    }
}

extern "C" void kernel_launch(void* const* d_in, const int* in_sizes, int n_in,
                              void* d_out, int out_size, void* d_ws, size_t ws_size,
                              hipStream_t stream) {
    const float* X    = (const float*)d_in[0];
    const float* Y    = (const float*)d_in[1];
    const float* stdp = (const float*)d_in[2];
    float* out  = (float*)d_out;
    double* acc = (double*)d_ws;

    hipMemsetAsync(acc, 0, 3 * sizeof(double), stream);

    dim3 block(256);
    dim3 grid(2, 510, 2);   // j-chunks, i rows, b-chunks (31 each)
    ns_loss_kernel<<<grid, block, 0, stream>>>(X, Y, stdp, acc);
    ns_finalize_kernel<<<1, 64, 0, stream>>>(acc, out);
}

// Round 2
// 182.478 us; speedup vs baseline: 1.2853x; 1.2853x over previous
//
#include <hip/hip_runtime.h>

// Navier-Stokes physics-informed loss (f32 in, scalar f32 out).
// x,y: (64,3,512,512). Interior: b in [1,62], i in [1,510], j in [1,510].
// r0 = |dudx + dvdy|
// r1 = |dudt + u*dudx + v*dudy + dpdx - MU*lap(u)|
// r2 = |dvdt + u*dvdx + v*dvdy + dpdy - MU*lap(v)|
// dudt = (u[b+1]-u[b-1])*32 ; d/dx,d/dy central *127.5 ; MU/DX^2 = 0.65025
//
// Layout: thread = (i-row, 4 consecutive j via float4). b is register-marched.
// Each wave = 64 lanes x float4 = 256 j's (half a row). j+-1 via shfl +
// 2 predicated edge scalars/wave. Blocks XCD-swizzled so adjacent i rows
// share an XCD L2 (kills the i+-1 cross-XCD re-fetch seen in FETCH_SIZE).

constexpr int Wd   = 512;
constexpr int CSTR = 512 * 512;
constexpr int BSTR = 3 * 512 * 512;

__device__ __forceinline__ float4 ld4(const float* p) {
    return *reinterpret_cast<const float4*>(p);
}
__device__ __forceinline__ float4 scale4(float4 a, float s) {
    return make_float4(a.x * s, a.y * s, a.z * s, a.w * s);
}

__device__ __forceinline__ void step_tensor(
    const float* __restrict__ T, int c, int jt,
    float s, float sdx, float slap,
    float4& um, float4& uc, float4& vm, float4& vc,
    float r0[4], float r1[4], float r2[4])
{
    const float4 unr = ld4(T + c + BSTR);
    const float4 vnr = ld4(T + c + BSTR + CSTR);
    const float4 uxp = ld4(T + c + Wd);
    const float4 uxm = ld4(T + c - Wd);
    const float4 vxp = ld4(T + c + CSTR + Wd);
    const float4 vxm = ld4(T + c + CSTR - Wd);
    const float4 pxp = ld4(T + c + 2 * CSTR + Wd);
    const float4 pxm = ld4(T + c + 2 * CSTR - Wd);
    const float4 pcr = ld4(T + c + 2 * CSTR);

    const float un[4] = {unr.x * s, unr.y * s, unr.z * s, unr.w * s};
    const float vn[4] = {vnr.x * s, vnr.y * s, vnr.z * s, vnr.w * s};

    // j-neighbors: shuffle across lanes; wave-boundary lanes load the edge.
    float u_l = __shfl_up(uc.w, 1);
    float v_l = __shfl_up(vc.w, 1);
    float p_l = __shfl_up(pcr.w, 1);
    float u_r = __shfl_down(uc.x, 1);
    float v_r = __shfl_down(vc.x, 1);
    float p_r = __shfl_down(pcr.x, 1);
    if (jt == 64) {  // lane 0 of right half-row: needs j0-1 = 255
        u_l = T[c - 1] * s;
        v_l = T[c + CSTR - 1] * s;
        p_l = T[c + 2 * CSTR - 1];
    }
    if (jt == 63) {  // lane 63 of left half-row: needs j0+4 = 256
        u_r = T[c + 4] * s;
        v_r = T[c + CSTR + 4] * s;
        p_r = T[c + 2 * CSTR + 4];
    }

    const float ucA[4] = {uc.x, uc.y, uc.z, uc.w};
    const float vcA[4] = {vc.x, vc.y, vc.z, vc.w};
    const float umA[4] = {um.x, um.y, um.z, um.w};
    const float vmA[4] = {vm.x, vm.y, vm.z, vm.w};
    const float ul[4]  = {u_l, uc.x, uc.y, uc.z};
    const float ur4[4] = {uc.y, uc.z, uc.w, u_r};
    const float vl[4]  = {v_l, vc.x, vc.y, vc.z};
    const float vr4[4] = {vc.y, vc.z, vc.w, v_r};
    const float pl[4]  = {p_l, pcr.x, pcr.y, pcr.z};
    const float pr4[4] = {pcr.y, pcr.z, pcr.w, p_r};
    const float uxpA[4] = {uxp.x, uxp.y, uxp.z, uxp.w};
    const float uxmA[4] = {uxm.x, uxm.y, uxm.z, uxm.w};
    const float vxpA[4] = {vxp.x, vxp.y, vxp.z, vxp.w};
    const float vxmA[4] = {vxm.x, vxm.y, vxm.z, vxm.w};
    const float pxpA[4] = {pxp.x, pxp.y, pxp.z, pxp.w};
    const float pxmA[4] = {pxm.x, pxm.y, pxm.z, pxm.w};

    #pragma unroll
    for (int k = 0; k < 4; ++k) {
        const float dudx = (uxpA[k] - uxmA[k]) * sdx;
        const float dvdx = (vxpA[k] - vxmA[k]) * sdx;
        const float dpdx = (pxpA[k] - pxmA[k]) * sdx;
        const float dudy = (ur4[k] - ul[k]) * 127.5f;   // already scaled by s
        const float dvdy = (vr4[k] - vl[k]) * 127.5f;
        const float dpdy = (pr4[k] - pl[k]) * sdx;      // p raw
        const float lapu = (uxpA[k] + uxmA[k]) * slap
                         + (ur4[k] + ul[k]) * 0.65025f - 2.601f * ucA[k];
        const float lapv = (vxpA[k] + vxmA[k]) * slap
                         + (vr4[k] + vl[k]) * 0.65025f - 2.601f * vcA[k];
        r0[k] = fabsf(dudx + dvdy);
        r1[k] = fabsf((un[k] - umA[k]) * 32.0f + ucA[k] * dudx + vcA[k] * dudy
                      + dpdx - lapu);
        r2[k] = fabsf((vn[k] - vmA[k]) * 32.0f + ucA[k] * dvdx + vcA[k] * dvdy
                      + dpdy - lapv);
    }

    um = uc; uc = make_float4(un[0], un[1], un[2], un[3]);
    vm = vc; vc = make_float4(vn[0], vn[1], vn[2], vn[3]);
}

__global__ __launch_bounds__(256, 4)
void ns_loss_kernel(const float* __restrict__ X, const float* __restrict__ Y,
                    const float* __restrict__ stdp, double* __restrict__ acc)
{
    const float s    = *stdp;
    const float sdx  = s * 127.5f;
    const float slap = s * 0.65025f;

    // Bijective XCD-chunked swizzle: XCD c owns a contiguous range of
    // (z-major, y-minor) work ids -> adjacent i rows share one L2.
    const int nwg  = gridDim.x;          // 1020
    const int q    = nwg >> 3;           // 127
    const int r    = nwg & 7;            // 4
    const int orig = blockIdx.x;
    const int xcd  = orig & 7;
    const int wg   = (xcd < r ? xcd * (q + 1) : r * (q + 1) + (xcd - r) * q)
                   + (orig >> 3);
    const int z = wg / 255;              // b-chunk 0..3
    const int y = wg % 255;              // i-pair 0..254

    const int tid = threadIdx.x;
    const int jt  = tid & 127;           // j-thread within row
    const int io  = tid >> 7;            // which of 2 rows
    const int i   = 1 + 2 * y + io;      // 1..510
    const int j0  = jt << 2;             // 0..508
    const int bs  = 1 + 16 * z;
    const int nsteps = min(16, 62 - 16 * z);

    int c = bs * BSTR + i * Wd + j0;

    float4 xum = scale4(ld4(X + c - BSTR), s);
    float4 xuc = scale4(ld4(X + c), s);
    float4 xvm = scale4(ld4(X + c - BSTR + CSTR), s);
    float4 xvc = scale4(ld4(X + c + CSTR), s);
    float4 yum = scale4(ld4(Y + c - BSTR), s);
    float4 yuc = scale4(ld4(Y + c), s);
    float4 yvm = scale4(ld4(Y + c - BSTR + CSTR), s);
    float4 yvc = scale4(ld4(Y + c + CSTR), s);

    const float w[4] = {(j0 != 0) ? 1.0f : 0.0f, 1.0f, 1.0f,
                        (j0 != 508) ? 1.0f : 0.0f};

    double s0 = 0.0, s1 = 0.0, s2 = 0.0;

    for (int it = 0; it < nsteps; ++it) {
        float r0x[4], r1x[4], r2x[4], r0y[4], r1y[4], r2y[4];
        step_tensor(X, c, jt, s, sdx, slap, xum, xuc, xvm, xvc, r0x, r1x, r2x);
        step_tensor(Y, c, jt, s, sdx, slap, yum, yuc, yvm, yvc, r0y, r1y, r2y);
        #pragma unroll
        for (int k = 0; k < 4; ++k) {
            const float e0 = (r0y[k] - r0x[k]) * w[k];
            const float e1 = (r1y[k] - r1x[k]) * w[k];
            const float e2 = (r2y[k] - r2x[k]) * w[k];
            s0 += (double)e0 * (double)e0;
            s1 += (double)e1 * (double)e1;
            s2 += (double)e2 * (double)e2;
        }
        c += BSTR;
    }

    // block reduction: wave shuffle -> LDS -> one atomic per block
    for (int o = 32; o > 0; o >>= 1) {
        s0 += __shfl_down(s0, o);
        s1 += __shfl_down(s1, o);
        s2 += __shfl_down(s2, o);
    }
    __shared__ double sm[3][4];
    const int wid = threadIdx.x >> 6, lane = threadIdx.x & 63;
    if (lane == 0) { sm[0][wid] = s0; sm[1][wid] = s1; sm[2][wid] = s2; }
    __syncthreads();
    if (threadIdx.x == 0) {
        atomicAdd(&acc[0], sm[0][0] + sm[0][1] + sm[0][2] + sm[0][3]);
        atomicAdd(&acc[1], sm[1][0] + sm[1][1] + sm[1][2] + sm[1][3]);
        atomicAdd(&acc[2], sm[2][0] + sm[2][1] + sm[2][2] + sm[2][3]);
    }
}

__global__ void ns_finalize_kernel(const double* __restrict__ acc,
                                   float* __restrict__ out)
{
    if (threadIdx.x == 0) {
        const double N = 62.0 * 510.0 * 510.0;
        out[0] = (float)(1.0e-3 * (acc[0] + acc[1] + acc[2]) / N);
    }
}

extern "C" void kernel_launch(void* const* d_in, const int* in_sizes, int n_in,
                              void* d_out, int out_size, void* d_ws, size_t ws_size,
                              hipStream_t stream) {
    const float* X    = (const float*)d_in[0];
    const float* Y    = (const float*)d_in[1];
    const float* stdp = (const float*)d_in[2];
    float* out  = (float*)d_out;
    double* acc = (double*)d_ws;

    hipMemsetAsync(acc, 0, 3 * sizeof(double), stream);

    dim3 block(256);
    dim3 grid(255 * 4);   // (i-pair) x (4 b-chunks), XCD-swizzled in-kernel
    ns_loss_kernel<<<grid, block, 0, stream>>>(X, Y, stdp, acc);
    ns_finalize_kernel<<<1, 64, 0, stream>>>(acc, out);
}